// Round 1
// baseline (5774.160 us; speedup 1.0000x reference)
//
#include <hip/hip_runtime.h>

#define HDIM 192
#define EPS 1e-5f

// ---------------------------------------------------------------------------
// GEMM: C[N,192] = A[N,K] @ W[K,192] (+ bias) (+ optional relu)
// Block: 256 threads, tile 64 rows x 192 cols, BK=32. Thread tile 4x12.
// ---------------------------------------------------------------------------
template<bool RELU>
__global__ __launch_bounds__(256) void gemm192(
    const float* __restrict__ A, const float* __restrict__ W,
    const float* __restrict__ bias, float* __restrict__ C,
    int N, int K)
{
    __shared__ float As[32][68];    // [k][row], pad->68 (272B rows, 16B aligned)
    __shared__ float Ws[32][192];   // [k][col]

    const int tid = threadIdx.x;
    const int ty = tid >> 4;        // 0..15 (row group)
    const int tx = tid & 15;        // 0..15 (col group)
    const int row0 = blockIdx.x * 64;

    float acc[4][12];
    #pragma unroll
    for (int i = 0; i < 4; ++i)
        #pragma unroll
        for (int j = 0; j < 12; ++j) acc[i][j] = 0.f;

    const int arow = tid >> 3;            // 0..31
    const int akq  = (tid & 7) << 2;      // 0,4,...,28

    for (int k0 = 0; k0 < K; k0 += 32) {
        // ---- stage A tile (64 rows x 32 k), transposed into As[k][row]
        #pragma unroll
        for (int p = 0; p < 2; ++p) {
            int rl = arow + p * 32;
            int rg = row0 + rl; if (rg >= N) rg = N - 1;   // clamp (stores guarded)
            float4 v = *(const float4*)(A + (size_t)rg * K + k0 + akq);
            As[akq + 0][rl] = v.x;
            As[akq + 1][rl] = v.y;
            As[akq + 2][rl] = v.z;
            As[akq + 3][rl] = v.w;
        }
        // ---- stage W tile (32 k x 192 cols), contiguous copy
        {
            const float4* Wg = (const float4*)(W + (size_t)k0 * HDIM);
            float4* WsV = (float4*)&Ws[0][0];
            #pragma unroll
            for (int i = 0; i < 6; ++i) WsV[tid + i * 256] = Wg[tid + i * 256];
        }
        __syncthreads();

        #pragma unroll
        for (int k = 0; k < 32; ++k) {
            float4 a  = *(const float4*)&As[k][ty * 4];
            float4 b0 = *(const float4*)&Ws[k][tx * 12];
            float4 b1 = *(const float4*)&Ws[k][tx * 12 + 4];
            float4 b2 = *(const float4*)&Ws[k][tx * 12 + 8];
            float av[4]  = {a.x, a.y, a.z, a.w};
            float bv[12] = {b0.x, b0.y, b0.z, b0.w,
                            b1.x, b1.y, b1.z, b1.w,
                            b2.x, b2.y, b2.z, b2.w};
            #pragma unroll
            for (int i = 0; i < 4; ++i)
                #pragma unroll
                for (int j = 0; j < 12; ++j)
                    acc[i][j] += av[i] * bv[j];
        }
        __syncthreads();
    }

    float bv[12];
    #pragma unroll
    for (int j = 0; j < 12; ++j) bv[j] = bias ? bias[tx * 12 + j] : 0.f;

    #pragma unroll
    for (int i = 0; i < 4; ++i) {
        int r = row0 + ty * 4 + i;
        if (r < N) {
            float* Cr = C + (size_t)r * HDIM + tx * 12;
            #pragma unroll
            for (int j = 0; j < 12; ++j) {
                float v = acc[i][j] + bv[j];
                if (RELU) v = fmaxf(v, 0.f);
                Cr[j] = v;
            }
        }
    }
}

// ---------------------------------------------------------------------------
// scatter: agg[dst] += h[src], parallel over (edge, 4-channel group)
// ---------------------------------------------------------------------------
__global__ __launch_bounds__(256) void scatter_add_k(
    const float* __restrict__ h, const int* __restrict__ src,
    const int* __restrict__ dst, float* __restrict__ agg, int E)
{
    int idx = blockIdx.x * 256 + threadIdx.x;   // over E*48
    if (idx >= E * 48) return;
    int e = idx / 48;
    int q = (idx % 48) * 4;
    int s = src[e], d = dst[e];
    float4 v = *(const float4*)(h + (size_t)s * HDIM + q);
    float* p = agg + (size_t)d * HDIM + q;
    atomicAdd(p + 0, v.x);
    atomicAdd(p + 1, v.y);
    atomicAdd(p + 2, v.z);
    atomicAdd(p + 3, v.w);
}

// ---------------------------------------------------------------------------
// batchnorm stats: per-channel sum and sumsq (block = 192 threads, 512 rows)
// ---------------------------------------------------------------------------
__global__ __launch_bounds__(192) void bn_stats_k(
    const float* __restrict__ h, float* __restrict__ sums, int N)
{
    int c = threadIdx.x;
    int r0 = blockIdx.x * 512;
    int r1 = min(r0 + 512, N);
    float s = 0.f, q = 0.f;
    for (int r = r0; r < r1; ++r) {
        float v = h[(size_t)r * HDIM + c];
        s += v; q += v * v;
    }
    atomicAdd(&sums[c], s);
    atomicAdd(&sums[HDIM + c], q);
}

__global__ void bn_finalize_k(const float* __restrict__ sums,
                              const float* __restrict__ gamma,
                              const float* __restrict__ beta,
                              float* __restrict__ ss, float invN)
{
    int c = threadIdx.x;   // 192
    float mu  = sums[c] * invN;
    float var = sums[HDIM + c] * invN - mu * mu;
    float sc  = gamma[c] * rsqrtf(var + EPS);
    ss[c]        = sc;
    ss[HDIM + c] = beta[c] - mu * sc;
}

__global__ __launch_bounds__(256) void bn_apply_k(
    const float* __restrict__ h, const float* __restrict__ ss,
    float* __restrict__ out, int N)
{
    int idx = blockIdx.x * 256 + threadIdx.x;   // over N*48 float4s
    if (idx >= N * 48) return;
    int q = (idx % 48) * 4;
    float4 v  = ((const float4*)h)[idx];
    float4 sc = *(const float4*)(ss + q);
    float4 sh = *(const float4*)(ss + HDIM + q);
    float4 o;
    o.x = fmaxf(v.x * sc.x + sh.x, 0.f);
    o.y = fmaxf(v.y * sc.y + sh.y, 0.f);
    o.z = fmaxf(v.z * sc.z + sh.z, 0.f);
    o.w = fmaxf(v.w * sc.w + sh.w, 0.f);
    ((float4*)out)[idx] = o;
}

// ---------------------------------------------------------------------------
// global mean pool
// ---------------------------------------------------------------------------
__global__ __launch_bounds__(256) void pool_sum_k(
    const float* __restrict__ x, const int* __restrict__ batch,
    float* __restrict__ gsum, int N)
{
    int idx = blockIdx.x * 256 + threadIdx.x;   // over N*48
    if (idx >= N * 48) return;
    int n = idx / 48;
    int q = (idx % 48) * 4;
    int b = batch[n];
    float4 v = ((const float4*)x)[idx];
    float* p = gsum + (size_t)b * HDIM + q;
    atomicAdd(p + 0, v.x);
    atomicAdd(p + 1, v.y);
    atomicAdd(p + 2, v.z);
    atomicAdd(p + 3, v.w);
}

__global__ __launch_bounds__(256) void pool_cnt_k(
    const int* __restrict__ batch, float* __restrict__ cnt, int N)
{
    int n = blockIdx.x * 256 + threadIdx.x;
    if (n < N) atomicAdd(&cnt[batch[n]], 1.0f);
}

__global__ __launch_bounds__(256) void pool_div_k(
    float* __restrict__ gsum, const float* __restrict__ cnt, int G)
{
    int idx = blockIdx.x * 256 + threadIdx.x;
    if (idx < G * HDIM) {
        int g = idx / HDIM;
        gsum[idx] /= fmaxf(cnt[g], 1.0f);
    }
}

// ---------------------------------------------------------------------------
// out[g] = dot(g2[g,:], Wout) + bout ; one wave per graph
// ---------------------------------------------------------------------------
__global__ __launch_bounds__(64) void out_dot_k(
    const float* __restrict__ g2, const float* __restrict__ Wout,
    const float* __restrict__ bout, float* __restrict__ out, int G)
{
    int gi = blockIdx.x;
    int t = threadIdx.x;
    const float* r = g2 + (size_t)gi * HDIM;
    float s = r[t] * Wout[t] + r[t + 64] * Wout[t + 64] + r[t + 128] * Wout[t + 128];
    #pragma unroll
    for (int off = 32; off > 0; off >>= 1) s += __shfl_down(s, off, 64);
    if (t == 0) out[gi] = s + bout[0];
}

// ---------------------------------------------------------------------------
extern "C" void kernel_launch(void* const* d_in, const int* in_sizes, int n_in,
                              void* d_out, int out_size, void* d_ws, size_t ws_size,
                              hipStream_t stream)
{
    const float* x      = (const float*)d_in[0];
    const int*   esrc   = (const int*)d_in[1];
    const int*   edst   = (const int*)d_in[2];
    const int*   batch  = (const int*)d_in[3];
    const float* Wrel0  = (const float*)d_in[4];
    const float* brel0  = (const float*)d_in[5];
    const float* Wroot0 = (const float*)d_in[6];
    const float* Wrel   = (const float*)d_in[7];
    const float* brel   = (const float*)d_in[8];
    const float* Wroot  = (const float*)d_in[9];
    const float* gamma  = (const float*)d_in[10];
    const float* beta   = (const float*)d_in[11];
    const float* Wh1    = (const float*)d_in[12];
    const float* bh1    = (const float*)d_in[13];
    const float* Wh2    = (const float*)d_in[14];
    const float* bh2    = (const float*)d_in[15];
    const float* Wout   = (const float*)d_in[16];
    const float* bout   = (const float*)d_in[17];
    float* out = (float*)d_out;

    const int N  = in_sizes[3];           // 100000
    const int E  = in_sizes[1];           // 400000
    const int K0 = in_sizes[0] / N;       // 32
    const int G  = out_size;              // 2000

    float* ws     = (float*)d_ws;
    float* bufx   = ws;                               // [N,192] layer activations
    float* bufh   = bufx + (size_t)N * HDIM;          // [N,192] lin_rel output
    float* bufa   = bufh + (size_t)N * HDIM;          // [N,192] aggregate
    float* gsum   = bufa + (size_t)N * HDIM;          // [G,192]
    float* cnt    = gsum + (size_t)G * HDIM;          // [G]
    float* g1     = cnt + G;                          // [G,192]
    float* g2     = g1 + (size_t)G * HDIM;            // [G,192]
    float* bnsums = g2 + (size_t)G * HDIM;            // [2*192] sum/sumsq
    float* bnss   = bnsums + 2 * HDIM;                // [2*192] scale/shift

    dim3 b256(256);
    const int gemmBlocksN = (N + 63) / 64;
    const int gemmBlocksG = (G + 63) / 64;
    const int ec = (E * 48 + 255) / 256;
    const int nc = (N * 48 + 255) / 256;

    for (int l = 0; l < 4; ++l) {
        const float* A  = (l == 0) ? x : bufx;
        const int    K  = (l == 0) ? K0 : HDIM;
        const float* Wr = (l == 0) ? Wrel0  : Wrel  + (size_t)(l - 1) * HDIM * HDIM;
        const float* br = (l == 0) ? brel0  : brel  + (size_t)(l - 1) * HDIM;
        const float* Wt = (l == 0) ? Wroot0 : Wroot + (size_t)(l - 1) * HDIM * HDIM;

        // agg = A @ Wroot   (full write, no memset needed)
        gemm192<false><<<gemmBlocksN, b256, 0, stream>>>(A, Wt, nullptr, bufa, N, K);
        // h = A @ Wrel + brel
        gemm192<false><<<gemmBlocksN, b256, 0, stream>>>(A, Wr, br, bufh, N, K);
        // agg[dst] += h[src]
        scatter_add_k<<<ec, b256, 0, stream>>>(bufh, esrc, edst, bufa, E);
        // batchnorm + relu -> bufx
        hipMemsetAsync(bnsums, 0, 2 * HDIM * sizeof(float), stream);
        bn_stats_k<<<(N + 511) / 512, dim3(192), 0, stream>>>(bufa, bnsums, N);
        bn_finalize_k<<<1, dim3(192), 0, stream>>>(bnsums, gamma + l * HDIM,
                                                   beta + l * HDIM, bnss, 1.0f / N);
        bn_apply_k<<<nc, b256, 0, stream>>>(bufa, bnss, bufx, N);
    }

    // global mean pool
    hipMemsetAsync(gsum, 0, ((size_t)G * HDIM + G) * sizeof(float), stream);
    pool_sum_k<<<nc, b256, 0, stream>>>(bufx, batch, gsum, N);
    pool_cnt_k<<<(N + 255) / 256, b256, 0, stream>>>(batch, cnt, N);
    pool_div_k<<<(G * HDIM + 255) / 256, b256, 0, stream>>>(gsum, cnt, G);

    // head MLP
    gemm192<true ><<<gemmBlocksG, b256, 0, stream>>>(gsum, Wh1, bh1, g1, G, HDIM);
    gemm192<false><<<gemmBlocksG, b256, 0, stream>>>(g1, Wh2, bh2, g2, G, HDIM);
    out_dot_k<<<G, dim3(64), 0, stream>>>(g2, Wout, bout, out, G);
}

// Round 2
// 1610.085 us; speedup vs baseline: 3.5862x; 3.5862x over previous
//
#include <hip/hip_runtime.h>

#define HDIM 192
#define EPS 1e-5f

// ---------------------------------------------------------------------------
// GEMM: C[N,192] = A[N,K] @ W[K,192] (+ bias) (+ optional relu)
// Block: 256 threads, tile 64 rows x 192 cols, BK=32. Thread tile 4x12.
// ---------------------------------------------------------------------------
template<bool RELU>
__global__ __launch_bounds__(256) void gemm192(
    const float* __restrict__ A, const float* __restrict__ W,
    const float* __restrict__ bias, float* __restrict__ C,
    int N, int K)
{
    __shared__ float As[32][68];
    __shared__ float Ws[32][192];

    const int tid = threadIdx.x;
    const int ty = tid >> 4;
    const int tx = tid & 15;
    const int row0 = blockIdx.x * 64;

    float acc[4][12];
    #pragma unroll
    for (int i = 0; i < 4; ++i)
        #pragma unroll
        for (int j = 0; j < 12; ++j) acc[i][j] = 0.f;

    const int arow = tid >> 3;
    const int akq  = (tid & 7) << 2;

    for (int k0 = 0; k0 < K; k0 += 32) {
        #pragma unroll
        for (int p = 0; p < 2; ++p) {
            int rl = arow + p * 32;
            int rg = row0 + rl; if (rg >= N) rg = N - 1;
            float4 v = *(const float4*)(A + (size_t)rg * K + k0 + akq);
            As[akq + 0][rl] = v.x;
            As[akq + 1][rl] = v.y;
            As[akq + 2][rl] = v.z;
            As[akq + 3][rl] = v.w;
        }
        {
            const float4* Wg = (const float4*)(W + (size_t)k0 * HDIM);
            float4* WsV = (float4*)&Ws[0][0];
            #pragma unroll
            for (int i = 0; i < 6; ++i) WsV[tid + i * 256] = Wg[tid + i * 256];
        }
        __syncthreads();

        #pragma unroll
        for (int k = 0; k < 32; ++k) {
            float4 a  = *(const float4*)&As[k][ty * 4];
            float4 b0 = *(const float4*)&Ws[k][tx * 12];
            float4 b1 = *(const float4*)&Ws[k][tx * 12 + 4];
            float4 b2 = *(const float4*)&Ws[k][tx * 12 + 8];
            float av[4]  = {a.x, a.y, a.z, a.w};
            float bv[12] = {b0.x, b0.y, b0.z, b0.w,
                            b1.x, b1.y, b1.z, b1.w,
                            b2.x, b2.y, b2.z, b2.w};
            #pragma unroll
            for (int i = 0; i < 4; ++i)
                #pragma unroll
                for (int j = 0; j < 12; ++j)
                    acc[i][j] += av[i] * bv[j];
        }
        __syncthreads();
    }

    float bv[12];
    #pragma unroll
    for (int j = 0; j < 12; ++j) bv[j] = bias ? bias[tx * 12 + j] : 0.f;

    #pragma unroll
    for (int i = 0; i < 4; ++i) {
        int r = row0 + ty * 4 + i;
        if (r < N) {
            float* Cr = C + (size_t)r * HDIM + tx * 12;
            #pragma unroll
            for (int j = 0; j < 12; ++j) {
                float v = acc[i][j] + bv[j];
                if (RELU) v = fmaxf(v, 0.f);
                Cr[j] = v;
            }
        }
    }
}

// ---------------------------------------------------------------------------
// Dual GEMM: C[N,192] = A1@W1 + A2@W2 + deg[row]*brel[col]
// Same tiling as gemm192; two sequential K-phases share the LDS buffers.
// ---------------------------------------------------------------------------
__global__ __launch_bounds__(256) void gemm_dual192(
    const float* __restrict__ A1, const float* __restrict__ W1,
    const float* __restrict__ A2, const float* __restrict__ W2,
    const float* __restrict__ degf, const float* __restrict__ brel,
    float* __restrict__ C, int N, int K)
{
    __shared__ float As[32][68];
    __shared__ float Ws[32][192];

    const int tid = threadIdx.x;
    const int ty = tid >> 4;
    const int tx = tid & 15;
    const int row0 = blockIdx.x * 64;

    float acc[4][12];
    #pragma unroll
    for (int i = 0; i < 4; ++i)
        #pragma unroll
        for (int j = 0; j < 12; ++j) acc[i][j] = 0.f;

    const int arow = tid >> 3;
    const int akq  = (tid & 7) << 2;

    for (int phase = 0; phase < 2; ++phase) {
        const float* A = phase ? A2 : A1;
        const float* W = phase ? W2 : W1;
        for (int k0 = 0; k0 < K; k0 += 32) {
            #pragma unroll
            for (int p = 0; p < 2; ++p) {
                int rl = arow + p * 32;
                int rg = row0 + rl; if (rg >= N) rg = N - 1;
                float4 v = *(const float4*)(A + (size_t)rg * K + k0 + akq);
                As[akq + 0][rl] = v.x;
                As[akq + 1][rl] = v.y;
                As[akq + 2][rl] = v.z;
                As[akq + 3][rl] = v.w;
            }
            {
                const float4* Wg = (const float4*)(W + (size_t)k0 * HDIM);
                float4* WsV = (float4*)&Ws[0][0];
                #pragma unroll
                for (int i = 0; i < 6; ++i) WsV[tid + i * 256] = Wg[tid + i * 256];
            }
            __syncthreads();

            #pragma unroll
            for (int k = 0; k < 32; ++k) {
                float4 a  = *(const float4*)&As[k][ty * 4];
                float4 b0 = *(const float4*)&Ws[k][tx * 12];
                float4 b1 = *(const float4*)&Ws[k][tx * 12 + 4];
                float4 b2 = *(const float4*)&Ws[k][tx * 12 + 8];
                float av[4]  = {a.x, a.y, a.z, a.w};
                float bv[12] = {b0.x, b0.y, b0.z, b0.w,
                                b1.x, b1.y, b1.z, b1.w,
                                b2.x, b2.y, b2.z, b2.w};
                #pragma unroll
                for (int i = 0; i < 4; ++i)
                    #pragma unroll
                    for (int j = 0; j < 12; ++j)
                        acc[i][j] += av[i] * bv[j];
            }
            __syncthreads();
        }
    }

    float bv[12];
    #pragma unroll
    for (int j = 0; j < 12; ++j) bv[j] = brel[tx * 12 + j];

    #pragma unroll
    for (int i = 0; i < 4; ++i) {
        int r = row0 + ty * 4 + i;
        if (r < N) {
            float d = degf[r];
            float* Cr = C + (size_t)r * HDIM + tx * 12;
            #pragma unroll
            for (int j = 0; j < 12; ++j)
                Cr[j] = acc[i][j] + d * bv[j];
        }
    }
}

// ---------------------------------------------------------------------------
// CSR construction from edge_dst
// ---------------------------------------------------------------------------
__global__ __launch_bounds__(256) void hist_k(
    const int* __restrict__ dst, int* __restrict__ deg, int E)
{
    int e = blockIdx.x * 256 + threadIdx.x;
    if (e < E) atomicAdd(&deg[dst[e]], 1);
}

__global__ __launch_bounds__(256) void block_sum_k(
    const int* __restrict__ deg, int* __restrict__ bsum, int N)
{
    __shared__ int s[256];
    int t = threadIdx.x;
    int n = blockIdx.x * 256 + t;
    s[t] = (n < N) ? deg[n] : 0;
    __syncthreads();
    for (int off = 128; off > 0; off >>= 1) {
        if (t < off) s[t] += s[t + off];
        __syncthreads();
    }
    if (t == 0) bsum[blockIdx.x] = s[0];
}

__global__ __launch_bounds__(512) void scan_bsum_k(int* __restrict__ bsum, int nb)
{
    __shared__ int s[512];
    int t = threadIdx.x;
    int v = (t < nb) ? bsum[t] : 0;
    s[t] = v;
    __syncthreads();
    for (int off = 1; off < 512; off <<= 1) {
        int u = (t >= off) ? s[t - off] : 0;
        __syncthreads();
        s[t] += u;
        __syncthreads();
    }
    if (t < nb) bsum[t] = s[t] - v;   // exclusive
}

__global__ __launch_bounds__(256) void row_ptr_k(
    const int* __restrict__ deg, const int* __restrict__ bsum,
    int* __restrict__ row_ptr, int* __restrict__ cursor,
    float* __restrict__ degf, int N, int E)
{
    __shared__ int s[256];
    int t = threadIdx.x;
    int n = blockIdx.x * 256 + t;
    int v = (n < N) ? deg[n] : 0;
    s[t] = v;
    __syncthreads();
    for (int off = 1; off < 256; off <<= 1) {
        int u = (t >= off) ? s[t - off] : 0;
        __syncthreads();
        s[t] += u;
        __syncthreads();
    }
    int ex = s[t] - v + bsum[blockIdx.x];
    if (n < N) {
        row_ptr[n] = ex;
        cursor[n]  = ex;
        degf[n]    = (float)v;
    }
    if (blockIdx.x == 0 && t == 0) row_ptr[N] = E;
}

__global__ __launch_bounds__(256) void fill_k(
    const int* __restrict__ src, const int* __restrict__ dst,
    int* __restrict__ cursor, int* __restrict__ col, int E)
{
    int e = blockIdx.x * 256 + threadIdx.x;
    if (e < E) {
        int p = atomicAdd(&cursor[dst[e]], 1);
        col[p] = src[e];
    }
}

// ---------------------------------------------------------------------------
// gather: out[n,:] = sum_{j in row_ptr[n]..row_ptr[n+1]} x[col[j],:]
// thread per (node, 4-channel quad)
// ---------------------------------------------------------------------------
__global__ __launch_bounds__(256) void gather_k(
    const float* __restrict__ x, const int* __restrict__ row_ptr,
    const int* __restrict__ col, float* __restrict__ out, int N, int K)
{
    const int WQ = K >> 2;
    int idx = blockIdx.x * 256 + threadIdx.x;
    if (idx >= N * WQ) return;
    int n = idx / WQ;
    int q = (idx - n * WQ) * 4;
    int j0 = row_ptr[n], j1 = row_ptr[n + 1];
    float4 acc = {0.f, 0.f, 0.f, 0.f};
    for (int j = j0; j < j1; ++j) {
        int s = col[j];
        float4 v = *(const float4*)(x + (size_t)s * K + q);
        acc.x += v.x; acc.y += v.y; acc.z += v.z; acc.w += v.w;
    }
    *(float4*)(out + (size_t)n * K + q) = acc;
}

// ---------------------------------------------------------------------------
// batchnorm
// ---------------------------------------------------------------------------
__global__ __launch_bounds__(192) void bn_stats_k(
    const float* __restrict__ h, float* __restrict__ sums, int N)
{
    int c = threadIdx.x;
    int r0 = blockIdx.x * 512;
    int r1 = min(r0 + 512, N);
    float s = 0.f, q = 0.f;
    for (int r = r0; r < r1; ++r) {
        float v = h[(size_t)r * HDIM + c];
        s += v; q += v * v;
    }
    atomicAdd(&sums[c], s);
    atomicAdd(&sums[HDIM + c], q);
}

__global__ void bn_finalize_k(const float* __restrict__ sums,
                              const float* __restrict__ gamma,
                              const float* __restrict__ beta,
                              float* __restrict__ ss, float invN)
{
    int c = threadIdx.x;
    float mu  = sums[c] * invN;
    float var = sums[HDIM + c] * invN - mu * mu;
    float sc  = gamma[c] * rsqrtf(var + EPS);
    ss[c]        = sc;
    ss[HDIM + c] = beta[c] - mu * sc;
}

__global__ __launch_bounds__(256) void bn_apply_k(
    const float* __restrict__ h, const float* __restrict__ ss,
    float* __restrict__ out, int N)
{
    int idx = blockIdx.x * 256 + threadIdx.x;
    if (idx >= N * 48) return;
    int q = (idx % 48) * 4;
    float4 v  = ((const float4*)h)[idx];
    float4 sc = *(const float4*)(ss + q);
    float4 sh = *(const float4*)(ss + HDIM + q);
    float4 o;
    o.x = fmaxf(v.x * sc.x + sh.x, 0.f);
    o.y = fmaxf(v.y * sc.y + sh.y, 0.f);
    o.z = fmaxf(v.z * sc.z + sh.z, 0.f);
    o.w = fmaxf(v.w * sc.w + sh.w, 0.f);
    ((float4*)out)[idx] = o;
}

// ---------------------------------------------------------------------------
// pool: batch is sorted -> per-graph contiguous row ranges
// ---------------------------------------------------------------------------
__global__ __launch_bounds__(256) void init_start_k(int* __restrict__ start, int G, int N)
{
    int g = blockIdx.x * 256 + threadIdx.x;
    if (g <= G) start[g] = N;
}

__global__ __launch_bounds__(256) void bound_k(
    const int* __restrict__ batch, int* __restrict__ start, int N)
{
    int n = blockIdx.x * 256 + threadIdx.x;
    if (n >= N) return;
    int b  = batch[n];
    int bp = (n == 0) ? -1 : batch[n - 1];
    for (int g = bp + 1; g <= b; ++g) start[g] = n;
}

__global__ __launch_bounds__(192) void pool_k(
    const float* __restrict__ x, const int* __restrict__ start,
    float* __restrict__ gout, int G)
{
    int g = blockIdx.x;
    int c = threadIdx.x;
    int r0 = start[g], r1 = start[g + 1];
    float s = 0.f;
    for (int r = r0; r < r1; ++r) s += x[(size_t)r * HDIM + c];
    float cnt = (float)(r1 - r0);
    gout[(size_t)g * HDIM + c] = s / fmaxf(cnt, 1.f);
}

// ---------------------------------------------------------------------------
__global__ __launch_bounds__(64) void out_dot_k(
    const float* __restrict__ g2, const float* __restrict__ Wout,
    const float* __restrict__ bout, float* __restrict__ out, int G)
{
    int gi = blockIdx.x;
    int t = threadIdx.x;
    const float* r = g2 + (size_t)gi * HDIM;
    float s = r[t] * Wout[t] + r[t + 64] * Wout[t + 64] + r[t + 128] * Wout[t + 128];
    #pragma unroll
    for (int off = 32; off > 0; off >>= 1) s += __shfl_down(s, off, 64);
    if (t == 0) out[gi] = s + bout[0];
}

// ---------------------------------------------------------------------------
extern "C" void kernel_launch(void* const* d_in, const int* in_sizes, int n_in,
                              void* d_out, int out_size, void* d_ws, size_t ws_size,
                              hipStream_t stream)
{
    const float* x      = (const float*)d_in[0];
    const int*   esrc   = (const int*)d_in[1];
    const int*   edst   = (const int*)d_in[2];
    const int*   batch  = (const int*)d_in[3];
    const float* Wrel0  = (const float*)d_in[4];
    const float* brel0  = (const float*)d_in[5];
    const float* Wroot0 = (const float*)d_in[6];
    const float* Wrel   = (const float*)d_in[7];
    const float* brel   = (const float*)d_in[8];
    const float* Wroot  = (const float*)d_in[9];
    const float* gamma  = (const float*)d_in[10];
    const float* beta   = (const float*)d_in[11];
    const float* Wh1    = (const float*)d_in[12];
    const float* bh1    = (const float*)d_in[13];
    const float* Wh2    = (const float*)d_in[14];
    const float* bh2    = (const float*)d_in[15];
    const float* Wout   = (const float*)d_in[16];
    const float* bout   = (const float*)d_in[17];
    float* out = (float*)d_out;

    const int N  = in_sizes[3];           // 100000
    const int E  = in_sizes[1];           // 400000
    const int K0 = in_sizes[0] / N;       // 32
    const int G  = out_size;              // 2000

    float* ws     = (float*)d_ws;
    float* bufx   = ws;                               // [N,192] activations
    float* bufg   = bufx + (size_t)N * HDIM;          // [N,192] gathered
    float* bufa   = bufg + (size_t)N * HDIM;          // [N,192] conv output
    float* gsum   = bufa + (size_t)N * HDIM;          // [G,192]
    float* g1     = gsum + (size_t)G * HDIM;          // [G,192]
    float* g2     = g1 + (size_t)G * HDIM;            // [G,192]
    float* bnsums = g2 + (size_t)G * HDIM;            // [2*192]
    float* bnss   = bnsums + 2 * HDIM;                // [2*192]
    float* degf   = bnss + 2 * HDIM;                  // [N]
    int*   deg    = (int*)(degf + N);                 // [N]
    int*   row_ptr= deg + N;                          // [N+1]
    int*   cursor = row_ptr + N + 1;                  // [N]
    int*   col    = cursor + N;                       // [E]
    int*   bsum   = col + E;                          // [~N/256+1]
    int*   start  = bsum + (N + 255) / 256 + 1;       // [G+1]

    dim3 b256(256);
    const int nBlocks  = (N + 255) / 256;
    const int eBlocks  = (E + 255) / 256;
    const int gemmBlocksN = (N + 63) / 64;
    const int gemmBlocksG = (G + 63) / 64;

    // ---- CSR build (once; reused by all 4 layers)
    hipMemsetAsync(deg, 0, N * sizeof(int), stream);
    hist_k<<<eBlocks, b256, 0, stream>>>(edst, deg, E);
    block_sum_k<<<nBlocks, b256, 0, stream>>>(deg, bsum, N);
    scan_bsum_k<<<1, dim3(512), 0, stream>>>(bsum, nBlocks);
    row_ptr_k<<<nBlocks, b256, 0, stream>>>(deg, bsum, row_ptr, cursor, degf, N, E);
    fill_k<<<eBlocks, b256, 0, stream>>>(esrc, edst, cursor, col, E);

    // ---- graph boundaries for pooling (batch sorted)
    init_start_k<<<(G + 256) / 256, b256, 0, stream>>>(start, G, N);
    bound_k<<<nBlocks, b256, 0, stream>>>(batch, start, N);

    // ---- layers
    for (int l = 0; l < 4; ++l) {
        const float* A  = (l == 0) ? x : bufx;
        const int    K  = (l == 0) ? K0 : HDIM;
        const float* Wr = (l == 0) ? Wrel0  : Wrel  + (size_t)(l - 1) * HDIM * HDIM;
        const float* br = (l == 0) ? brel0  : brel  + (size_t)(l - 1) * HDIM;
        const float* Wt = (l == 0) ? Wroot0 : Wroot + (size_t)(l - 1) * HDIM * HDIM;

        // xa = gather(A)  (scatter-first: segment_sum commutes with the linear)
        int gq = N * (K >> 2);
        gather_k<<<(gq + 255) / 256, b256, 0, stream>>>(A, row_ptr, col, bufg, N, K);
        // bufa = xa@Wrel + A@Wroot + deg*brel
        gemm_dual192<<<gemmBlocksN, b256, 0, stream>>>(bufg, Wr, A, Wt, degf, br,
                                                       bufa, N, K);
        // batchnorm + relu -> bufx
        hipMemsetAsync(bnsums, 0, 2 * HDIM * sizeof(float), stream);
        bn_stats_k<<<(N + 511) / 512, dim3(192), 0, stream>>>(bufa, bnsums, N);
        bn_finalize_k<<<1, dim3(192), 0, stream>>>(bnsums, gamma + l * HDIM,
                                                   beta + l * HDIM, bnss, 1.0f / N);
        bn_apply_k<<<(N * 48 + 255) / 256, b256, 0, stream>>>(bufa, bnss, bufx, N);
    }

    // ---- global mean pool (contiguous ranges, no atomics)
    pool_k<<<G, dim3(192), 0, stream>>>(bufx, start, gsum, G);

    // ---- head MLP
    gemm192<true ><<<gemmBlocksG, b256, 0, stream>>>(gsum, Wh1, bh1, g1, G, HDIM);
    gemm192<false><<<gemmBlocksG, b256, 0, stream>>>(g1, Wh2, bh2, g2, G, HDIM);
    out_dot_k<<<G, dim3(64), 0, stream>>>(g2, Wout, bout, out, G);
}

// Round 3
// 1359.071 us; speedup vs baseline: 4.2486x; 1.1847x over previous
//
#include <hip/hip_runtime.h>

#define HDIM 192
#define EPS 1e-5f

typedef __attribute__((ext_vector_type(8))) short short8;
typedef __attribute__((ext_vector_type(4))) float floatx4;

__device__ __forceinline__ float bf2f(ushort h) {
    union { uint u; float f; } c; c.u = ((uint)h) << 16; return c.f;
}
__device__ __forceinline__ ushort f2bf(float x) {
    union { float f; uint u; } c; c.f = x; return (ushort)(c.u >> 16);
}
// split fp32 into bf16 hi + bf16 lo (truncation; residual ~2^-16 relative)
__device__ __forceinline__ void splitf(float x, ushort& hi, ushort& lo) {
    hi = f2bf(x);
    lo = f2bf(x - bf2f(hi));
}

// ---------------------------------------------------------------------------
// Weight prep: W[K,192] fp32 (nmat stacked) -> frag-ordered split planes.
// Per k-chunk (32 k): [plane(hi,lo)][ct(12)][lane(64)][j(8)] = 12288 ushorts.
// col = ct*16 + (lane&15), k = kc*32 + (lane>>4)*8 + j   (B-frag layout of
// mfma_f32_16x16x32_bf16: n=lane&15, k=(lane>>4)*8+j)
// ---------------------------------------------------------------------------
__global__ __launch_bounds__(256) void prep_w_k(
    const float* __restrict__ W, ushort* __restrict__ Wf, int K, int nmat)
{
    int perMat = (K >> 5) * 12 * 64;
    int idx = blockIdx.x * 256 + threadIdx.x;
    if (idx >= perMat * nmat) return;
    int mat = idx / perMat;
    int r = idx - mat * perMat;
    int lane = r & 63;
    int ct = (r >> 6) % 12;
    int kc = r / (12 * 64);
    int col = ct * 16 + (lane & 15);
    int kb  = kc * 32 + (lane >> 4) * 8;
    const float* Wm = W + (size_t)mat * K * HDIM;
    ushort* base = Wf + (size_t)mat * K * HDIM * 2;
    size_t o = (size_t)kc * 12288 + (size_t)(ct * 64 + lane) * 8;
    #pragma unroll
    for (int j = 0; j < 8; ++j) {
        ushort hi, lo;
        splitf(Wm[(size_t)(kb + j) * HDIM + col], hi, lo);
        base[o + j]        = hi;
        base[o + 6144 + j] = lo;
    }
}

// ---------------------------------------------------------------------------
// split fp32 array -> bf16 hi/lo planes (8 elements per thread)
// ---------------------------------------------------------------------------
__global__ __launch_bounds__(256) void split_k(
    const float* __restrict__ src, ushort* __restrict__ hi,
    ushort* __restrict__ lo, int n8)
{
    int idx = blockIdx.x * 256 + threadIdx.x;
    if (idx >= n8) return;
    float4 v0 = ((const float4*)src)[idx * 2];
    float4 v1 = ((const float4*)src)[idx * 2 + 1];
    float v[8] = {v0.x, v0.y, v0.z, v0.w, v1.x, v1.y, v1.z, v1.w};
    ushort h[8], l[8];
    #pragma unroll
    for (int t = 0; t < 8; ++t) splitf(v[t], h[t], l[t]);
    uint4 ph, pl;
    ph.x = h[0] | ((uint)h[1] << 16); ph.y = h[2] | ((uint)h[3] << 16);
    ph.z = h[4] | ((uint)h[5] << 16); ph.w = h[6] | ((uint)h[7] << 16);
    pl.x = l[0] | ((uint)l[1] << 16); pl.y = l[2] | ((uint)l[3] << 16);
    pl.z = l[4] | ((uint)l[5] << 16); pl.w = l[6] | ((uint)l[7] << 16);
    *(uint4*)(hi + (size_t)idx * 8) = ph;
    *(uint4*)(lo + (size_t)idx * 8) = pl;
}

// ---------------------------------------------------------------------------
// MFMA GEMM: C[N,192] = A1@W1 (+ A2@W2) + bias-term.
// A planes: bf16 hi/lo, row-major [N,K]. W frag-ordered (prep_w_k).
// Block: 256 thr / 4 waves, tile 128 rows x 192 cols.
// Wave (r2=w&1, c2=w>>1): rows r2*64..+64, cols c2*96..+96.
// 3-term split product: Ah*Bh + Al*Bh + Ah*Bl.
// ---------------------------------------------------------------------------
template<bool DUAL, bool RELU, bool DEG>
__global__ __launch_bounds__(256) void gemm_mfma_k(
    const ushort* __restrict__ A1h, const ushort* __restrict__ A1l,
    const ushort* __restrict__ W1f,
    const ushort* __restrict__ A2h, const ushort* __restrict__ A2l,
    const ushort* __restrict__ W2f,
    const float* __restrict__ degf, const float* __restrict__ bias,
    float* __restrict__ C, int N, int K)
{
    __shared__ ushort Bs[12288];   // 24 KB, frag-major: conflict-free b128 reads
    const int tid  = threadIdx.x;
    const int wave = tid >> 6;
    const int lane = tid & 63;
    const int r2 = wave & 1;
    const int c2 = wave >> 1;
    const int row0 = blockIdx.x * 128 + r2 * 64;
    const int m16 = lane & 15;
    const int g4  = lane >> 4;

    floatx4 acc[4][6];
    #pragma unroll
    for (int s = 0; s < 4; ++s)
        #pragma unroll
        for (int ct = 0; ct < 6; ++ct) acc[s][ct] = (floatx4){0.f, 0.f, 0.f, 0.f};

    const int nkc = K >> 5;
    const int nphase = DUAL ? 2 : 1;
    for (int phase = 0; phase < nphase; ++phase) {
        const ushort* Ah = phase ? A2h : A1h;
        const ushort* Al = phase ? A2l : A1l;
        const ushort* Wf = phase ? W2f : W1f;
        for (int kc = 0; kc < nkc; ++kc) {
            // stage B tile (24 KB contiguous) into LDS
            const uint4* src = (const uint4*)(Wf + (size_t)kc * 12288);
            uint4* dst = (uint4*)Bs;
            #pragma unroll
            for (int i = 0; i < 6; ++i) dst[tid + i * 256] = src[tid + i * 256];
            __syncthreads();
            // A fragments (global, 16B contiguous per lane)
            short8 ah[4], al[4];
            #pragma unroll
            for (int s = 0; s < 4; ++s) {
                int rr = row0 + s * 16 + m16; if (rr >= N) rr = N - 1;
                size_t off = (size_t)rr * K + kc * 32 + g4 * 8;
                ah[s] = *(const short8*)(Ah + off);
                al[s] = *(const short8*)(Al + off);
            }
            #pragma unroll
            for (int ct = 0; ct < 6; ++ct) {
                int cti = c2 * 6 + ct;
                short8 bh = *(const short8*)&Bs[(size_t)(cti * 64 + lane) * 8];
                short8 bl = *(const short8*)&Bs[6144 + (size_t)(cti * 64 + lane) * 8];
                #pragma unroll
                for (int s = 0; s < 4; ++s) {
                    acc[s][ct] = __builtin_amdgcn_mfma_f32_16x16x32_bf16(ah[s], bh, acc[s][ct], 0, 0, 0);
                    acc[s][ct] = __builtin_amdgcn_mfma_f32_16x16x32_bf16(al[s], bh, acc[s][ct], 0, 0, 0);
                    acc[s][ct] = __builtin_amdgcn_mfma_f32_16x16x32_bf16(ah[s], bl, acc[s][ct], 0, 0, 0);
                }
            }
            __syncthreads();
        }
    }
    // epilogue: C/D layout col=lane&15, row=(lane>>4)*4+reg  [m89]
    #pragma unroll
    for (int ct = 0; ct < 6; ++ct) {
        int col = c2 * 96 + ct * 16 + m16;
        float bv = bias ? bias[col] : 0.f;
        #pragma unroll
        for (int s = 0; s < 4; ++s) {
            #pragma unroll
            for (int reg = 0; reg < 4; ++reg) {
                int rr = row0 + s * 16 + g4 * 4 + reg;
                if (rr < N) {
                    float v = acc[s][ct][reg] + (DEG ? degf[rr] * bv : bv);
                    if (RELU) v = fmaxf(v, 0.f);
                    C[(size_t)rr * HDIM + col] = v;
                }
            }
        }
    }
}

// ---------------------------------------------------------------------------
// CSR construction from edge_dst
// ---------------------------------------------------------------------------
__global__ __launch_bounds__(256) void hist_k(
    const int* __restrict__ dst, int* __restrict__ deg, int E)
{
    int e = blockIdx.x * 256 + threadIdx.x;
    if (e < E) atomicAdd(&deg[dst[e]], 1);
}

__global__ __launch_bounds__(256) void block_sum_k(
    const int* __restrict__ deg, int* __restrict__ bsum, int N)
{
    __shared__ int s[256];
    int t = threadIdx.x;
    int n = blockIdx.x * 256 + t;
    s[t] = (n < N) ? deg[n] : 0;
    __syncthreads();
    for (int off = 128; off > 0; off >>= 1) {
        if (t < off) s[t] += s[t + off];
        __syncthreads();
    }
    if (t == 0) bsum[blockIdx.x] = s[0];
}

__global__ __launch_bounds__(512) void scan_bsum_k(int* __restrict__ bsum, int nb)
{
    __shared__ int s[512];
    int t = threadIdx.x;
    int v = (t < nb) ? bsum[t] : 0;
    s[t] = v;
    __syncthreads();
    for (int off = 1; off < 512; off <<= 1) {
        int u = (t >= off) ? s[t - off] : 0;
        __syncthreads();
        s[t] += u;
        __syncthreads();
    }
    if (t < nb) bsum[t] = s[t] - v;   // exclusive
}

__global__ __launch_bounds__(256) void row_ptr_k(
    const int* __restrict__ deg, const int* __restrict__ bsum,
    int* __restrict__ row_ptr, int* __restrict__ cursor,
    float* __restrict__ degf, int N, int E)
{
    __shared__ int s[256];
    int t = threadIdx.x;
    int n = blockIdx.x * 256 + t;
    int v = (n < N) ? deg[n] : 0;
    s[t] = v;
    __syncthreads();
    for (int off = 1; off < 256; off <<= 1) {
        int u = (t >= off) ? s[t - off] : 0;
        __syncthreads();
        s[t] += u;
        __syncthreads();
    }
    int ex = s[t] - v + bsum[blockIdx.x];
    if (n < N) {
        row_ptr[n] = ex;
        cursor[n]  = ex;
        degf[n]    = (float)v;
    }
    if (blockIdx.x == 0 && t == 0) row_ptr[N] = E;
}

__global__ __launch_bounds__(256) void fill_k(
    const int* __restrict__ src, const int* __restrict__ dst,
    int* __restrict__ cursor, int* __restrict__ col, int E)
{
    int e = blockIdx.x * 256 + threadIdx.x;
    if (e < E) {
        int p = atomicAdd(&cursor[dst[e]], 1);
        col[p] = src[e];
    }
}

// ---------------------------------------------------------------------------
// gather on split planes: g[n] = sum_{j} (hi+lo)[col[j]]; output re-split.
// Thread per (node, 8-channel group).
// ---------------------------------------------------------------------------
__global__ __launch_bounds__(256) void gather_split_k(
    const ushort* __restrict__ xh, const ushort* __restrict__ xl,
    const int* __restrict__ row_ptr, const int* __restrict__ col,
    ushort* __restrict__ gh, ushort* __restrict__ gl, int N, int K)
{
    int WQ = K >> 3;
    int idx = blockIdx.x * 256 + threadIdx.x;
    if (idx >= N * WQ) return;
    int n = idx / WQ;
    int q = (idx - n * WQ) * 8;
    int j0 = row_ptr[n], j1 = row_ptr[n + 1];
    float acc[8] = {0.f,0.f,0.f,0.f,0.f,0.f,0.f,0.f};
    for (int j = j0; j < j1; ++j) {
        int s = col[j];
        uint4 hv = *(const uint4*)(xh + (size_t)s * K + q);
        uint4 lv = *(const uint4*)(xl + (size_t)s * K + q);
        uint hu[4] = {hv.x, hv.y, hv.z, hv.w};
        uint lu[4] = {lv.x, lv.y, lv.z, lv.w};
        #pragma unroll
        for (int t = 0; t < 4; ++t) {
            acc[2*t]   += bf2f((ushort)(hu[t] & 0xffffu)) + bf2f((ushort)(lu[t] & 0xffffu));
            acc[2*t+1] += bf2f((ushort)(hu[t] >> 16))     + bf2f((ushort)(lu[t] >> 16));
        }
    }
    ushort oh[8], ol[8];
    #pragma unroll
    for (int t = 0; t < 8; ++t) splitf(acc[t], oh[t], ol[t]);
    uint4 ph, pl;
    ph.x = oh[0] | ((uint)oh[1] << 16); ph.y = oh[2] | ((uint)oh[3] << 16);
    ph.z = oh[4] | ((uint)oh[5] << 16); ph.w = oh[6] | ((uint)oh[7] << 16);
    pl.x = ol[0] | ((uint)ol[1] << 16); pl.y = ol[2] | ((uint)ol[3] << 16);
    pl.z = ol[4] | ((uint)ol[5] << 16); pl.w = ol[6] | ((uint)ol[7] << 16);
    *(uint4*)(gh + (size_t)n * K + q) = ph;
    *(uint4*)(gl + (size_t)n * K + q) = pl;
}

// ---------------------------------------------------------------------------
// batchnorm
// ---------------------------------------------------------------------------
__global__ __launch_bounds__(192) void bn_stats_k(
    const float* __restrict__ h, float* __restrict__ sums, int N)
{
    int c = threadIdx.x;
    int r0 = blockIdx.x * 512;
    int r1 = min(r0 + 512, N);
    float s = 0.f, q = 0.f;
    for (int r = r0; r < r1; ++r) {
        float v = h[(size_t)r * HDIM + c];
        s += v; q += v * v;
    }
    atomicAdd(&sums[c], s);
    atomicAdd(&sums[HDIM + c], q);
}

__global__ void bn_finalize_k(const float* __restrict__ sums,
                              const float* __restrict__ gamma,
                              const float* __restrict__ beta,
                              float* __restrict__ ss, float invN)
{
    int c = threadIdx.x;
    float mu  = sums[c] * invN;
    float var = sums[HDIM + c] * invN - mu * mu;
    float sc  = gamma[c] * rsqrtf(var + EPS);
    ss[c]        = sc;
    ss[HDIM + c] = beta[c] - mu * sc;
}

// apply BN + ReLU, emit split bf16 planes. Thread per 8 channels.
__global__ __launch_bounds__(256) void bn_apply_split_k(
    const float* __restrict__ h, const float* __restrict__ ss,
    ushort* __restrict__ xh, ushort* __restrict__ xl, int N)
{
    int idx = blockIdx.x * 256 + threadIdx.x;   // over N*24
    if (idx >= N * 24) return;
    int q = (idx % 24) * 8;
    float4 v0 = ((const float4*)h)[idx * 2];
    float4 v1 = ((const float4*)h)[idx * 2 + 1];
    float v[8] = {v0.x, v0.y, v0.z, v0.w, v1.x, v1.y, v1.z, v1.w};
    ushort oh[8], ol[8];
    #pragma unroll
    for (int t = 0; t < 8; ++t) {
        float r = fmaxf(v[t] * ss[q + t] + ss[HDIM + q + t], 0.f);
        splitf(r, oh[t], ol[t]);
    }
    uint4 ph, pl;
    ph.x = oh[0] | ((uint)oh[1] << 16); ph.y = oh[2] | ((uint)oh[3] << 16);
    ph.z = oh[4] | ((uint)oh[5] << 16); ph.w = oh[6] | ((uint)oh[7] << 16);
    pl.x = ol[0] | ((uint)ol[1] << 16); pl.y = ol[2] | ((uint)ol[3] << 16);
    pl.z = ol[4] | ((uint)ol[5] << 16); pl.w = ol[6] | ((uint)ol[7] << 16);
    *(uint4*)(xh + (size_t)idx * 8) = ph;
    *(uint4*)(xl + (size_t)idx * 8) = pl;
}

// ---------------------------------------------------------------------------
// pool over contiguous per-graph row ranges (batch sorted), split-plane input
// ---------------------------------------------------------------------------
__global__ __launch_bounds__(256) void init_start_k(int* __restrict__ start, int G, int N)
{
    int g = blockIdx.x * 256 + threadIdx.x;
    if (g <= G) start[g] = N;
}

__global__ __launch_bounds__(256) void bound_k(
    const int* __restrict__ batch, int* __restrict__ start, int N)
{
    int n = blockIdx.x * 256 + threadIdx.x;
    if (n >= N) return;
    int b  = batch[n];
    int bp = (n == 0) ? -1 : batch[n - 1];
    for (int g = bp + 1; g <= b; ++g) start[g] = n;
}

__global__ __launch_bounds__(192) void pool_k(
    const ushort* __restrict__ xh, const ushort* __restrict__ xl,
    const int* __restrict__ start, float* __restrict__ gout, int G)
{
    int g = blockIdx.x;
    int c = threadIdx.x;
    int r0 = start[g], r1 = start[g + 1];
    float s = 0.f;
    for (int r = r0; r < r1; ++r) {
        size_t o = (size_t)r * HDIM + c;
        s += bf2f(xh[o]) + bf2f(xl[o]);
    }
    float cnt = (float)(r1 - r0);
    gout[(size_t)g * HDIM + c] = s / fmaxf(cnt, 1.f);
}

// ---------------------------------------------------------------------------
__global__ __launch_bounds__(64) void out_dot_k(
    const float* __restrict__ g2, const float* __restrict__ Wout,
    const float* __restrict__ bout, float* __restrict__ out, int G)
{
    int gi = blockIdx.x;
    int t = threadIdx.x;
    const float* r = g2 + (size_t)gi * HDIM;
    float s = r[t] * Wout[t] + r[t + 64] * Wout[t + 64] + r[t + 128] * Wout[t + 128];
    #pragma unroll
    for (int off = 32; off > 0; off >>= 1) s += __shfl_down(s, off, 64);
    if (t == 0) out[gi] = s + bout[0];
}

// ---------------------------------------------------------------------------
extern "C" void kernel_launch(void* const* d_in, const int* in_sizes, int n_in,
                              void* d_out, int out_size, void* d_ws, size_t ws_size,
                              hipStream_t stream)
{
    const float* x      = (const float*)d_in[0];
    const int*   esrc   = (const int*)d_in[1];
    const int*   edst   = (const int*)d_in[2];
    const int*   batch  = (const int*)d_in[3];
    const float* Wrel0  = (const float*)d_in[4];
    const float* brel0  = (const float*)d_in[5];
    const float* Wroot0 = (const float*)d_in[6];
    const float* Wrel   = (const float*)d_in[7];
    const float* brel   = (const float*)d_in[8];
    const float* Wroot  = (const float*)d_in[9];
    const float* gamma  = (const float*)d_in[10];
    const float* beta   = (const float*)d_in[11];
    const float* Wh1    = (const float*)d_in[12];
    const float* bh1    = (const float*)d_in[13];
    const float* Wh2    = (const float*)d_in[14];
    const float* bh2    = (const float*)d_in[15];
    const float* Wout   = (const float*)d_in[16];
    const float* bout   = (const float*)d_in[17];
    float* out = (float*)d_out;

    const int N  = in_sizes[3];           // 100000
    const int E  = in_sizes[1];           // 400000
    const int K0 = in_sizes[0] / N;       // 32
    const int G  = out_size;              // 2000
    const int nBlocks = (N + 255) / 256;

    // ---- workspace carve-up (256B aligned chunks)
    char* p = (char*)d_ws;
    auto carve = [&](size_t bytes) -> void* {
        void* r = (void*)p; p += (bytes + 255) & ~(size_t)255; return r;
    };
    float*  bufa  = (float*) carve((size_t)N * HDIM * 4);
    ushort* xh    = (ushort*)carve((size_t)N * HDIM * 2);
    ushort* xl    = (ushort*)carve((size_t)N * HDIM * 2);
    ushort* gh    = (ushort*)carve((size_t)N * HDIM * 2);
    ushort* gl    = (ushort*)carve((size_t)N * HDIM * 2);
    float*  gsum  = (float*) carve((size_t)G * HDIM * 4);
    float*  g1    = (float*) carve((size_t)G * HDIM * 4);
    float*  g2    = (float*) carve((size_t)G * HDIM * 4);
    ushort* gsh   = (ushort*)carve((size_t)G * HDIM * 2);
    ushort* gsl   = (ushort*)carve((size_t)G * HDIM * 2);
    ushort* g1h   = (ushort*)carve((size_t)G * HDIM * 2);
    ushort* g1l   = (ushort*)carve((size_t)G * HDIM * 2);
    float*  bnsums= (float*) carve(2 * HDIM * 4);
    float*  bnss  = (float*) carve(2 * HDIM * 4);
    float*  degf  = (float*) carve((size_t)N * 4);
    int*    deg   = (int*)   carve((size_t)N * 4);
    int*    row_ptr=(int*)   carve((size_t)(N + 1) * 4);
    int*    cursor= (int*)   carve((size_t)N * 4);
    int*    col   = (int*)   carve((size_t)E * 4);
    int*    bsum  = (int*)   carve((size_t)nBlocks * 4);
    int*    start = (int*)   carve((size_t)(G + 1) * 4);
    ushort* Wrel0f= (ushort*)carve((size_t)K0 * HDIM * 2 * 2);
    ushort* Wroot0f=(ushort*)carve((size_t)K0 * HDIM * 2 * 2);
    ushort* Wrelf = (ushort*)carve((size_t)3 * HDIM * HDIM * 2 * 2);
    ushort* Wrootf= (ushort*)carve((size_t)3 * HDIM * HDIM * 2 * 2);
    ushort* Wh1f  = (ushort*)carve((size_t)HDIM * HDIM * 2 * 2);
    ushort* Wh2f  = (ushort*)carve((size_t)HDIM * HDIM * 2 * 2);

    dim3 b256(256);
    const int eBlocks = (E + 255) / 256;
    const int gemmN = (N + 127) / 128;
    const int gemmG = (G + 127) / 128;

    // ---- weight prep (frag-ordered hi/lo split)
    {
        int t0 = (K0 >> 5) * 12 * 64;       // per-mat threads, K=32
        int t1 = (HDIM >> 5) * 12 * 64;     // per-mat threads, K=192
        prep_w_k<<<(t0 + 255) / 256, b256, 0, stream>>>(Wrel0,  Wrel0f,  K0, 1);
        prep_w_k<<<(t0 + 255) / 256, b256, 0, stream>>>(Wroot0, Wroot0f, K0, 1);
        prep_w_k<<<(3 * t1 + 255) / 256, b256, 0, stream>>>(Wrel,  Wrelf,  HDIM, 3);
        prep_w_k<<<(3 * t1 + 255) / 256, b256, 0, stream>>>(Wroot, Wrootf, HDIM, 3);
        prep_w_k<<<(t1 + 255) / 256, b256, 0, stream>>>(Wh1, Wh1f, HDIM, 1);
        prep_w_k<<<(t1 + 255) / 256, b256, 0, stream>>>(Wh2, Wh2f, HDIM, 1);
    }
    // ---- split input x -> planes (K0 layout)
    split_k<<<((N * K0 / 8) + 255) / 256, b256, 0, stream>>>(x, xh, xl, N * K0 / 8);

    // ---- CSR build
    hipMemsetAsync(deg, 0, N * sizeof(int), stream);
    hist_k<<<eBlocks, b256, 0, stream>>>(edst, deg, E);
    block_sum_k<<<nBlocks, b256, 0, stream>>>(deg, bsum, N);
    scan_bsum_k<<<1, dim3(512), 0, stream>>>(bsum, nBlocks);
    row_ptr_k<<<nBlocks, b256, 0, stream>>>(deg, bsum, row_ptr, cursor, degf, N, E);
    fill_k<<<eBlocks, b256, 0, stream>>>(esrc, edst, cursor, col, E);

    // ---- graph boundaries for pooling
    init_start_k<<<(G + 256) / 256, b256, 0, stream>>>(start, G, N);
    bound_k<<<nBlocks, b256, 0, stream>>>(batch, start, N);

    // ---- layers
    for (int l = 0; l < 4; ++l) {
        const int K = (l == 0) ? K0 : HDIM;
        const ushort* Wrf = (l == 0) ? Wrel0f  : Wrelf  + (size_t)(l - 1) * HDIM * HDIM * 2;
        const ushort* Wtf = (l == 0) ? Wroot0f : Wrootf + (size_t)(l - 1) * HDIM * HDIM * 2;
        const float*  br  = (l == 0) ? brel0   : brel   + (size_t)(l - 1) * HDIM;

        int gthreads = N * (K >> 3);
        gather_split_k<<<(gthreads + 255) / 256, b256, 0, stream>>>(
            xh, xl, row_ptr, col, gh, gl, N, K);
        gemm_mfma_k<true, false, true><<<gemmN, b256, 0, stream>>>(
            gh, gl, Wrf, xh, xl, Wtf, degf, br, bufa, N, K);
        hipMemsetAsync(bnsums, 0, 2 * HDIM * sizeof(float), stream);
        bn_stats_k<<<(N + 511) / 512, dim3(192), 0, stream>>>(bufa, bnsums, N);
        bn_finalize_k<<<1, dim3(192), 0, stream>>>(bnsums, gamma + l * HDIM,
                                                   beta + l * HDIM, bnss, 1.0f / N);
        bn_apply_split_k<<<(N * 24 + 255) / 256, b256, 0, stream>>>(bufa, bnss, xh, xl, N);
    }

    // ---- pool
    pool_k<<<G, dim3(192), 0, stream>>>(xh, xl, start, gsum, G);

    // ---- head MLP (MFMA path)
    split_k<<<((G * HDIM / 8) + 255) / 256, b256, 0, stream>>>(gsum, gsh, gsl, G * HDIM / 8);
    gemm_mfma_k<false, true, false><<<gemmG, b256, 0, stream>>>(
        gsh, gsl, Wh1f, nullptr, nullptr, nullptr, nullptr, bh1, g1, G, HDIM);
    split_k<<<((G * HDIM / 8) + 255) / 256, b256, 0, stream>>>(g1, g1h, g1l, G * HDIM / 8);
    gemm_mfma_k<false, false, false><<<gemmG, b256, 0, stream>>>(
        g1h, g1l, Wh2f, nullptr, nullptr, nullptr, nullptr, bh2, g2, G, HDIM);
    out_dot_k<<<G, dim3(64), 0, stream>>>(g2, Wout, bout, out, G);
}

// Round 4
// 912.233 us; speedup vs baseline: 6.3297x; 1.4898x over previous
//
#include <hip/hip_runtime.h>

#define HDIM 192
#define EPS 1e-5f

typedef __attribute__((ext_vector_type(8))) short short8;
typedef __attribute__((ext_vector_type(4))) float floatx4;

__device__ __forceinline__ float bf2f(ushort h) {
    union { uint u; float f; } c; c.u = ((uint)h) << 16; return c.f;
}
__device__ __forceinline__ ushort f2bf(float x) {
    union { float f; uint u; } c; c.f = x; return (ushort)(c.u >> 16);
}
// split fp32 into bf16 hi + bf16 lo (truncation; residual ~2^-16 relative)
__device__ __forceinline__ void splitf(float x, ushort& hi, ushort& lo) {
    hi = f2bf(x);
    lo = f2bf(x - bf2f(hi));
}

// ---------------------------------------------------------------------------
// Weight prep: W[K,192] fp32 (nmat stacked) -> frag-ordered split planes.
// Per k-chunk (32 k): [plane(hi,lo)][ct(12)][lane(64)][j(8)] = 12288 ushorts.
// ---------------------------------------------------------------------------
__global__ __launch_bounds__(256) void prep_w_k(
    const float* __restrict__ W, ushort* __restrict__ Wf, int K, int nmat)
{
    int perMat = (K >> 5) * 12 * 64;
    int idx = blockIdx.x * 256 + threadIdx.x;
    if (idx >= perMat * nmat) return;
    int mat = idx / perMat;
    int r = idx - mat * perMat;
    int lane = r & 63;
    int ct = (r >> 6) % 12;
    int kc = r / (12 * 64);
    int col = ct * 16 + (lane & 15);
    int kb  = kc * 32 + (lane >> 4) * 8;
    const float* Wm = W + (size_t)mat * K * HDIM;
    ushort* base = Wf + (size_t)mat * K * HDIM * 2;
    size_t o = (size_t)kc * 12288 + (size_t)(ct * 64 + lane) * 8;
    #pragma unroll
    for (int j = 0; j < 8; ++j) {
        ushort hi, lo;
        splitf(Wm[(size_t)(kb + j) * HDIM + col], hi, lo);
        base[o + j]        = hi;
        base[o + 6144 + j] = lo;
    }
}

// ---------------------------------------------------------------------------
// split fp32 array -> bf16 hi/lo planes (8 elements per thread)
// ---------------------------------------------------------------------------
__global__ __launch_bounds__(256) void split_k(
    const float* __restrict__ src, ushort* __restrict__ hi,
    ushort* __restrict__ lo, int n8)
{
    int idx = blockIdx.x * 256 + threadIdx.x;
    if (idx >= n8) return;
    float4 v0 = ((const float4*)src)[idx * 2];
    float4 v1 = ((const float4*)src)[idx * 2 + 1];
    float v[8] = {v0.x, v0.y, v0.z, v0.w, v1.x, v1.y, v1.z, v1.w};
    ushort h[8], l[8];
    #pragma unroll
    for (int t = 0; t < 8; ++t) splitf(v[t], h[t], l[t]);
    uint4 ph, pl;
    ph.x = h[0] | ((uint)h[1] << 16); ph.y = h[2] | ((uint)h[3] << 16);
    ph.z = h[4] | ((uint)h[5] << 16); ph.w = h[6] | ((uint)h[7] << 16);
    pl.x = l[0] | ((uint)l[1] << 16); pl.y = l[2] | ((uint)l[3] << 16);
    pl.z = l[4] | ((uint)l[5] << 16); pl.w = l[6] | ((uint)l[7] << 16);
    *(uint4*)(hi + (size_t)idx * 8) = ph;
    *(uint4*)(lo + (size_t)idx * 8) = pl;
}

// ---------------------------------------------------------------------------
// MFMA GEMM: C[N,192] = A1@W1 (+ A2@W2) + bias-term, optional fused BN stats.
// Block: 256 thr / 4 waves, tile 128 rows x 192 cols.
// 3-term split product: Ah*Bh + Al*Bh + Ah*Bl.
// STATS: per-column sum/sumsq of C accumulated into stats[0..191]/[192..383].
// ---------------------------------------------------------------------------
template<bool DUAL, bool RELU, bool DEG, bool STATS>
__global__ __launch_bounds__(256) void gemm_mfma_k(
    const ushort* __restrict__ A1h, const ushort* __restrict__ A1l,
    const ushort* __restrict__ W1f,
    const ushort* __restrict__ A2h, const ushort* __restrict__ A2l,
    const ushort* __restrict__ W2f,
    const float* __restrict__ degf, const float* __restrict__ bias,
    float* __restrict__ C, float* __restrict__ stats, int N, int K)
{
    __shared__ ushort Bs[12288];   // 24 KB, frag-major: conflict-free b128 reads
    __shared__ float sstat[2][HDIM];
    const int tid  = threadIdx.x;
    const int wave = tid >> 6;
    const int lane = tid & 63;
    const int r2 = wave & 1;
    const int c2 = wave >> 1;
    const int row0 = blockIdx.x * 128 + r2 * 64;
    const int m16 = lane & 15;
    const int g4  = lane >> 4;

    if (STATS && tid < HDIM) { sstat[0][tid] = 0.f; sstat[1][tid] = 0.f; }

    floatx4 acc[4][6];
    #pragma unroll
    for (int s = 0; s < 4; ++s)
        #pragma unroll
        for (int ct = 0; ct < 6; ++ct) acc[s][ct] = (floatx4){0.f, 0.f, 0.f, 0.f};

    const int nkc = K >> 5;
    const int nphase = DUAL ? 2 : 1;
    for (int phase = 0; phase < nphase; ++phase) {
        const ushort* Ah = phase ? A2h : A1h;
        const ushort* Al = phase ? A2l : A1l;
        const ushort* Wf = phase ? W2f : W1f;
        for (int kc = 0; kc < nkc; ++kc) {
            const uint4* src = (const uint4*)(Wf + (size_t)kc * 12288);
            uint4* dst = (uint4*)Bs;
            #pragma unroll
            for (int i = 0; i < 6; ++i) dst[tid + i * 256] = src[tid + i * 256];
            __syncthreads();
            short8 ah[4], al[4];
            #pragma unroll
            for (int s = 0; s < 4; ++s) {
                int rr = row0 + s * 16 + m16; if (rr >= N) rr = N - 1;
                size_t off = (size_t)rr * K + kc * 32 + g4 * 8;
                ah[s] = *(const short8*)(Ah + off);
                al[s] = *(const short8*)(Al + off);
            }
            #pragma unroll
            for (int ct = 0; ct < 6; ++ct) {
                int cti = c2 * 6 + ct;
                short8 bh = *(const short8*)&Bs[(size_t)(cti * 64 + lane) * 8];
                short8 bl = *(const short8*)&Bs[6144 + (size_t)(cti * 64 + lane) * 8];
                #pragma unroll
                for (int s = 0; s < 4; ++s) {
                    acc[s][ct] = __builtin_amdgcn_mfma_f32_16x16x32_bf16(ah[s], bh, acc[s][ct], 0, 0, 0);
                    acc[s][ct] = __builtin_amdgcn_mfma_f32_16x16x32_bf16(al[s], bh, acc[s][ct], 0, 0, 0);
                    acc[s][ct] = __builtin_amdgcn_mfma_f32_16x16x32_bf16(ah[s], bl, acc[s][ct], 0, 0, 0);
                }
            }
            __syncthreads();
        }
    }
    // epilogue: C/D layout col=lane&15, row=(lane>>4)*4+reg  [m89]
    #pragma unroll
    for (int ct = 0; ct < 6; ++ct) {
        int col = c2 * 96 + ct * 16 + m16;
        float bv = bias ? bias[col] : 0.f;
        float lsum = 0.f, lsq = 0.f;
        #pragma unroll
        for (int s = 0; s < 4; ++s) {
            #pragma unroll
            for (int reg = 0; reg < 4; ++reg) {
                int rr = row0 + s * 16 + g4 * 4 + reg;
                if (rr < N) {
                    float v = acc[s][ct][reg] + (DEG ? degf[rr] * bv : bv);
                    if (STATS) { lsum += v; lsq += v * v; }
                    if (RELU) v = fmaxf(v, 0.f);
                    C[(size_t)rr * HDIM + col] = v;
                }
            }
        }
        if (STATS) {
            // reduce over the 4 row-groups (lanes differing in bits 4,5)
            lsum += __shfl_xor(lsum, 16); lsum += __shfl_xor(lsum, 32);
            lsq  += __shfl_xor(lsq, 16);  lsq  += __shfl_xor(lsq, 32);
            if (g4 == 0) {
                atomicAdd(&sstat[0][col], lsum);
                atomicAdd(&sstat[1][col], lsq);
            }
        }
    }
    if (STATS) {
        __syncthreads();
        if (tid < HDIM) {
            atomicAdd(&stats[tid], sstat[0][tid]);
            atomicAdd(&stats[HDIM + tid], sstat[1][tid]);
        }
    }
}

// ---------------------------------------------------------------------------
// CSR construction from edge_dst
// ---------------------------------------------------------------------------
__global__ __launch_bounds__(256) void hist_k(
    const int* __restrict__ dst, int* __restrict__ deg, int E)
{
    int e = blockIdx.x * 256 + threadIdx.x;
    if (e < E) atomicAdd(&deg[dst[e]], 1);
}

__global__ __launch_bounds__(256) void block_sum_k(
    const int* __restrict__ deg, int* __restrict__ bsum, int N)
{
    __shared__ int s[256];
    int t = threadIdx.x;
    int n = blockIdx.x * 256 + t;
    s[t] = (n < N) ? deg[n] : 0;
    __syncthreads();
    for (int off = 128; off > 0; off >>= 1) {
        if (t < off) s[t] += s[t + off];
        __syncthreads();
    }
    if (t == 0) bsum[blockIdx.x] = s[0];
}

__global__ __launch_bounds__(512) void scan_bsum_k(int* __restrict__ bsum, int nb)
{
    __shared__ int s[512];
    int t = threadIdx.x;
    int v = (t < nb) ? bsum[t] : 0;
    s[t] = v;
    __syncthreads();
    for (int off = 1; off < 512; off <<= 1) {
        int u = (t >= off) ? s[t - off] : 0;
        __syncthreads();
        s[t] += u;
        __syncthreads();
    }
    if (t < nb) bsum[t] = s[t] - v;   // exclusive
}

__global__ __launch_bounds__(256) void row_ptr_k(
    const int* __restrict__ deg, const int* __restrict__ bsum,
    int* __restrict__ row_ptr, int* __restrict__ cursor,
    float* __restrict__ degf, int N, int E)
{
    __shared__ int s[256];
    int t = threadIdx.x;
    int n = blockIdx.x * 256 + t;
    int v = (n < N) ? deg[n] : 0;
    s[t] = v;
    __syncthreads();
    for (int off = 1; off < 256; off <<= 1) {
        int u = (t >= off) ? s[t - off] : 0;
        __syncthreads();
        s[t] += u;
        __syncthreads();
    }
    int ex = s[t] - v + bsum[blockIdx.x];
    if (n < N) {
        row_ptr[n] = ex;
        cursor[n]  = ex;
        degf[n]    = (float)v;
    }
    if (blockIdx.x == 0 && t == 0) row_ptr[N] = E;
}

__global__ __launch_bounds__(256) void fill_k(
    const int* __restrict__ src, const int* __restrict__ dst,
    int* __restrict__ cursor, int* __restrict__ col, int E)
{
    int e = blockIdx.x * 256 + threadIdx.x;
    if (e < E) {
        int p = atomicAdd(&cursor[dst[e]], 1);
        col[p] = src[e];
    }
}

// ---------------------------------------------------------------------------
// gather on split planes: g[n] = sum_{j} (hi+lo)[col[j]]; output re-split.
// ---------------------------------------------------------------------------
__global__ __launch_bounds__(256) void gather_split_k(
    const ushort* __restrict__ xh, const ushort* __restrict__ xl,
    const int* __restrict__ row_ptr, const int* __restrict__ col,
    ushort* __restrict__ gh, ushort* __restrict__ gl, int N, int K)
{
    int WQ = K >> 3;
    int idx = blockIdx.x * 256 + threadIdx.x;
    if (idx >= N * WQ) return;
    int n = idx / WQ;
    int q = (idx - n * WQ) * 8;
    int j0 = row_ptr[n], j1 = row_ptr[n + 1];
    float acc[8] = {0.f,0.f,0.f,0.f,0.f,0.f,0.f,0.f};
    for (int j = j0; j < j1; ++j) {
        int s = col[j];
        uint4 hv = *(const uint4*)(xh + (size_t)s * K + q);
        uint4 lv = *(const uint4*)(xl + (size_t)s * K + q);
        uint hu[4] = {hv.x, hv.y, hv.z, hv.w};
        uint lu[4] = {lv.x, lv.y, lv.z, lv.w};
        #pragma unroll
        for (int t = 0; t < 4; ++t) {
            acc[2*t]   += bf2f((ushort)(hu[t] & 0xffffu)) + bf2f((ushort)(lu[t] & 0xffffu));
            acc[2*t+1] += bf2f((ushort)(hu[t] >> 16))     + bf2f((ushort)(lu[t] >> 16));
        }
    }
    ushort oh[8], ol[8];
    #pragma unroll
    for (int t = 0; t < 8; ++t) splitf(acc[t], oh[t], ol[t]);
    uint4 ph, pl;
    ph.x = oh[0] | ((uint)oh[1] << 16); ph.y = oh[2] | ((uint)oh[3] << 16);
    ph.z = oh[4] | ((uint)oh[5] << 16); ph.w = oh[6] | ((uint)oh[7] << 16);
    pl.x = ol[0] | ((uint)ol[1] << 16); pl.y = ol[2] | ((uint)ol[3] << 16);
    pl.z = ol[4] | ((uint)ol[5] << 16); pl.w = ol[6] | ((uint)ol[7] << 16);
    *(uint4*)(gh + (size_t)n * K + q) = ph;
    *(uint4*)(gl + (size_t)n * K + q) = pl;
}

// ---------------------------------------------------------------------------
// batchnorm finalize + apply
// ---------------------------------------------------------------------------
__global__ void bn_finalize_k(const float* __restrict__ sums,
                              const float* __restrict__ gamma,
                              const float* __restrict__ beta,
                              float* __restrict__ ss, float invN)
{
    int c = threadIdx.x;
    float mu  = sums[c] * invN;
    float var = sums[HDIM + c] * invN - mu * mu;
    float sc  = gamma[c] * rsqrtf(var + EPS);
    ss[c]        = sc;
    ss[HDIM + c] = beta[c] - mu * sc;
}

__global__ __launch_bounds__(256) void bn_apply_split_k(
    const float* __restrict__ h, const float* __restrict__ ss,
    ushort* __restrict__ xh, ushort* __restrict__ xl, int N)
{
    int idx = blockIdx.x * 256 + threadIdx.x;   // over N*24
    if (idx >= N * 24) return;
    int q = (idx % 24) * 8;
    float4 v0 = ((const float4*)h)[idx * 2];
    float4 v1 = ((const float4*)h)[idx * 2 + 1];
    float v[8] = {v0.x, v0.y, v0.z, v0.w, v1.x, v1.y, v1.z, v1.w};
    ushort oh[8], ol[8];
    #pragma unroll
    for (int t = 0; t < 8; ++t) {
        float r = fmaxf(v[t] * ss[q + t] + ss[HDIM + q + t], 0.f);
        splitf(r, oh[t], ol[t]);
    }
    uint4 ph, pl;
    ph.x = oh[0] | ((uint)oh[1] << 16); ph.y = oh[2] | ((uint)oh[3] << 16);
    ph.z = oh[4] | ((uint)oh[5] << 16); ph.w = oh[6] | ((uint)oh[7] << 16);
    pl.x = ol[0] | ((uint)ol[1] << 16); pl.y = ol[2] | ((uint)ol[3] << 16);
    pl.z = ol[4] | ((uint)ol[5] << 16); pl.w = ol[6] | ((uint)ol[7] << 16);
    *(uint4*)(xh + (size_t)idx * 8) = ph;
    *(uint4*)(xl + (size_t)idx * 8) = pl;
}

// ---------------------------------------------------------------------------
// pool over contiguous per-graph row ranges (batch sorted)
// ---------------------------------------------------------------------------
__global__ __launch_bounds__(256) void init_start_k(int* __restrict__ start, int G, int N)
{
    int g = blockIdx.x * 256 + threadIdx.x;
    if (g <= G) start[g] = N;
}

__global__ __launch_bounds__(256) void bound_k(
    const int* __restrict__ batch, int* __restrict__ start, int N)
{
    int n = blockIdx.x * 256 + threadIdx.x;
    if (n >= N) return;
    int b  = batch[n];
    int bp = (n == 0) ? -1 : batch[n - 1];
    for (int g = bp + 1; g <= b; ++g) start[g] = n;
}

__global__ __launch_bounds__(192) void pool_k(
    const ushort* __restrict__ xh, const ushort* __restrict__ xl,
    const int* __restrict__ start, float* __restrict__ gout, int G)
{
    int g = blockIdx.x;
    int c = threadIdx.x;
    int r0 = start[g], r1 = start[g + 1];
    float s = 0.f;
    for (int r = r0; r < r1; ++r) {
        size_t o = (size_t)r * HDIM + c;
        s += bf2f(xh[o]) + bf2f(xl[o]);
    }
    float cnt = (float)(r1 - r0);
    gout[(size_t)g * HDIM + c] = s / fmaxf(cnt, 1.f);
}

// ---------------------------------------------------------------------------
__global__ __launch_bounds__(64) void out_dot_k(
    const float* __restrict__ g2, const float* __restrict__ Wout,
    const float* __restrict__ bout, float* __restrict__ out, int G)
{
    int gi = blockIdx.x;
    int t = threadIdx.x;
    const float* r = g2 + (size_t)gi * HDIM;
    float s = r[t] * Wout[t] + r[t + 64] * Wout[t + 64] + r[t + 128] * Wout[t + 128];
    #pragma unroll
    for (int off = 32; off > 0; off >>= 1) s += __shfl_down(s, off, 64);
    if (t == 0) out[gi] = s + bout[0];
}

// ---------------------------------------------------------------------------
extern "C" void kernel_launch(void* const* d_in, const int* in_sizes, int n_in,
                              void* d_out, int out_size, void* d_ws, size_t ws_size,
                              hipStream_t stream)
{
    const float* x      = (const float*)d_in[0];
    const int*   esrc   = (const int*)d_in[1];
    const int*   edst   = (const int*)d_in[2];
    const int*   batch  = (const int*)d_in[3];
    const float* Wrel0  = (const float*)d_in[4];
    const float* brel0  = (const float*)d_in[5];
    const float* Wroot0 = (const float*)d_in[6];
    const float* Wrel   = (const float*)d_in[7];
    const float* brel   = (const float*)d_in[8];
    const float* Wroot  = (const float*)d_in[9];
    const float* gamma  = (const float*)d_in[10];
    const float* beta   = (const float*)d_in[11];
    const float* Wh1    = (const float*)d_in[12];
    const float* bh1    = (const float*)d_in[13];
    const float* Wh2    = (const float*)d_in[14];
    const float* bh2    = (const float*)d_in[15];
    const float* Wout   = (const float*)d_in[16];
    const float* bout   = (const float*)d_in[17];
    float* out = (float*)d_out;

    const int N  = in_sizes[3];           // 100000
    const int E  = in_sizes[1];           // 400000
    const int K0 = in_sizes[0] / N;       // 32
    const int G  = out_size;              // 2000
    const int nBlocks = (N + 255) / 256;

    char* p = (char*)d_ws;
    auto carve = [&](size_t bytes) -> void* {
        void* r = (void*)p; p += (bytes + 255) & ~(size_t)255; return r;
    };
    float*  bufa  = (float*) carve((size_t)N * HDIM * 4);
    ushort* xh    = (ushort*)carve((size_t)N * HDIM * 2);
    ushort* xl    = (ushort*)carve((size_t)N * HDIM * 2);
    ushort* gh    = (ushort*)carve((size_t)N * HDIM * 2);
    ushort* gl    = (ushort*)carve((size_t)N * HDIM * 2);
    float*  gsum  = (float*) carve((size_t)G * HDIM * 4);
    float*  g1    = (float*) carve((size_t)G * HDIM * 4);
    float*  g2    = (float*) carve((size_t)G * HDIM * 4);
    ushort* gsh   = (ushort*)carve((size_t)G * HDIM * 2);
    ushort* gsl   = (ushort*)carve((size_t)G * HDIM * 2);
    ushort* g1h   = (ushort*)carve((size_t)G * HDIM * 2);
    ushort* g1l   = (ushort*)carve((size_t)G * HDIM * 2);
    float*  bnsums= (float*) carve(2 * HDIM * 4);
    float*  bnss  = (float*) carve(2 * HDIM * 4);
    float*  degf  = (float*) carve((size_t)N * 4);
    int*    deg   = (int*)   carve((size_t)N * 4);
    int*    row_ptr=(int*)   carve((size_t)(N + 1) * 4);
    int*    cursor= (int*)   carve((size_t)N * 4);
    int*    col   = (int*)   carve((size_t)E * 4);
    int*    bsum  = (int*)   carve((size_t)nBlocks * 4);
    int*    start = (int*)   carve((size_t)(G + 1) * 4);
    ushort* Wrel0f= (ushort*)carve((size_t)K0 * HDIM * 2 * 2);
    ushort* Wroot0f=(ushort*)carve((size_t)K0 * HDIM * 2 * 2);
    ushort* Wrelf = (ushort*)carve((size_t)3 * HDIM * HDIM * 2 * 2);
    ushort* Wrootf= (ushort*)carve((size_t)3 * HDIM * HDIM * 2 * 2);
    ushort* Wh1f  = (ushort*)carve((size_t)HDIM * HDIM * 2 * 2);
    ushort* Wh2f  = (ushort*)carve((size_t)HDIM * HDIM * 2 * 2);

    dim3 b256(256);
    const int eBlocks = (E + 255) / 256;
    const int gemmN = (N + 127) / 128;
    const int gemmG = (G + 127) / 128;

    // ---- weight prep (frag-ordered hi/lo split)
    {
        int t0 = (K0 >> 5) * 12 * 64;
        int t1 = (HDIM >> 5) * 12 * 64;
        prep_w_k<<<(t0 + 255) / 256, b256, 0, stream>>>(Wrel0,  Wrel0f,  K0, 1);
        prep_w_k<<<(t0 + 255) / 256, b256, 0, stream>>>(Wroot0, Wroot0f, K0, 1);
        prep_w_k<<<(3 * t1 + 255) / 256, b256, 0, stream>>>(Wrel,  Wrelf,  HDIM, 3);
        prep_w_k<<<(3 * t1 + 255) / 256, b256, 0, stream>>>(Wroot, Wrootf, HDIM, 3);
        prep_w_k<<<(t1 + 255) / 256, b256, 0, stream>>>(Wh1, Wh1f, HDIM, 1);
        prep_w_k<<<(t1 + 255) / 256, b256, 0, stream>>>(Wh2, Wh2f, HDIM, 1);
    }
    split_k<<<((N * K0 / 8) + 255) / 256, b256, 0, stream>>>(x, xh, xl, N * K0 / 8);

    // ---- CSR build
    hipMemsetAsync(deg, 0, N * sizeof(int), stream);
    hist_k<<<eBlocks, b256, 0, stream>>>(edst, deg, E);
    block_sum_k<<<nBlocks, b256, 0, stream>>>(deg, bsum, N);
    scan_bsum_k<<<1, dim3(512), 0, stream>>>(bsum, nBlocks);
    row_ptr_k<<<nBlocks, b256, 0, stream>>>(deg, bsum, row_ptr, cursor, degf, N, E);
    fill_k<<<eBlocks, b256, 0, stream>>>(esrc, edst, cursor, col, E);

    // ---- graph boundaries for pooling
    init_start_k<<<(G + 256) / 256, b256, 0, stream>>>(start, G, N);
    bound_k<<<nBlocks, b256, 0, stream>>>(batch, start, N);

    // ---- layers
    for (int l = 0; l < 4; ++l) {
        const int K = (l == 0) ? K0 : HDIM;
        const ushort* Wrf = (l == 0) ? Wrel0f  : Wrelf  + (size_t)(l - 1) * HDIM * HDIM * 2;
        const ushort* Wtf = (l == 0) ? Wroot0f : Wrootf + (size_t)(l - 1) * HDIM * HDIM * 2;
        const float*  br  = (l == 0) ? brel0   : brel   + (size_t)(l - 1) * HDIM;

        int gthreads = N * (K >> 3);
        gather_split_k<<<(gthreads + 255) / 256, b256, 0, stream>>>(
            xh, xl, row_ptr, col, gh, gl, N, K);
        hipMemsetAsync(bnsums, 0, 2 * HDIM * sizeof(float), stream);
        // GEMM with fused BN-stats epilogue
        gemm_mfma_k<true, false, true, true><<<gemmN, b256, 0, stream>>>(
            gh, gl, Wrf, xh, xl, Wtf, degf, br, bufa, bnsums, N, K);
        bn_finalize_k<<<1, dim3(192), 0, stream>>>(bnsums, gamma + l * HDIM,
                                                   beta + l * HDIM, bnss, 1.0f / N);
        bn_apply_split_k<<<(N * 24 + 255) / 256, b256, 0, stream>>>(bufa, bnss, xh, xl, N);
    }

    // ---- pool
    pool_k<<<G, dim3(192), 0, stream>>>(xh, xl, start, gsum, G);

    // ---- head MLP (MFMA path)
    split_k<<<((G * HDIM / 8) + 255) / 256, b256, 0, stream>>>(gsum, gsh, gsl, G * HDIM / 8);
    gemm_mfma_k<false, true, false, false><<<gemmG, b256, 0, stream>>>(
        gsh, gsl, Wh1f, nullptr, nullptr, nullptr, nullptr, bh1, g1, nullptr, G, HDIM);
    split_k<<<((G * HDIM / 8) + 255) / 256, b256, 0, stream>>>(g1, g1h, g1l, G * HDIM / 8);
    gemm_mfma_k<false, false, false, false><<<gemmG, b256, 0, stream>>>(
        g1h, g1l, Wh2f, nullptr, nullptr, nullptr, nullptr, bh2, g2, nullptr, G, HDIM);
    out_dot_k<<<G, dim3(64), 0, stream>>>(g2, Wout, bout, out, G);
}